// Round 1
// baseline (236.702 us; speedup 1.0000x reference)
//
#include <hip/hip_runtime.h>

#define N_ROWS 8192
#define DIMS   512
#define TILE   64
#define KSPLIT 8
#define KCHUNK (N_ROWS / KSPLIT)   // 1024
#define KB     16
#define NT     256

// Computes partial A = X^T X and B = Y^T Y tiles over a K-chunk.
// Grid: (64 tiles = 8x8, KSPLIT). Each block: 64x64 tile of both A and B.
// Per-thread 4x4 register tile per matrix -> 32 FMA per k-step vs 4 LDS b128
// reads -> VALU-bound on the fp32 pipe.
__global__ __launch_bounds__(NT) void syrk_kernel(
    const float* __restrict__ X, const float* __restrict__ Y,
    float* __restrict__ Abase, float* __restrict__ Bbase, int useSlabs)
{
    const int tid = threadIdx.x;
    const int ta  = blockIdx.x >> 3;   // tile row (a-stripe)
    const int tb  = blockIdx.x & 7;    // tile col (b-stripe)
    const int s   = blockIdx.y;        // k-split index
    const int ca  = tid & 15;          // a float4-group (0..15)
    const int cb  = tid >> 4;          // b float4-group (0..15)

    __shared__ float4 sXA[KB * 16];
    __shared__ float4 sXB[KB * 16];
    __shared__ float4 sYA[KB * 16];
    __shared__ float4 sYB[KB * 16];

    const float4* Xv = (const float4*)X;
    const float4* Yv = (const float4*)Y;

    float aA[4][4] = {};
    float aB[4][4] = {};

    const int r0     = s * KCHUNK;
    const int rowOfT = tid >> 4;   // staging row within KB-chunk
    const int colOfT = tid & 15;   // staging float4-col within 64-col stripe

    for (int it = 0; it < KCHUNK / KB; ++it) {
        const int row  = r0 + it * KB + rowOfT;
        const int base = row * (DIMS / 4);
        __syncthreads();
        sXA[tid] = Xv[base + ta * 16 + colOfT];
        sXB[tid] = Xv[base + tb * 16 + colOfT];
        sYA[tid] = Yv[base + ta * 16 + colOfT];
        sYB[tid] = Yv[base + tb * 16 + colOfT];
        __syncthreads();
#pragma unroll
        for (int k = 0; k < KB; ++k) {
            float4 xa4 = sXA[k * 16 + ca];
            float4 xb4 = sXB[k * 16 + cb];
            float4 ya4 = sYA[k * 16 + ca];
            float4 yb4 = sYB[k * 16 + cb];
            float xa[4] = {xa4.x, xa4.y, xa4.z, xa4.w};
            float xb[4] = {xb4.x, xb4.y, xb4.z, xb4.w};
            float ya[4] = {ya4.x, ya4.y, ya4.z, ya4.w};
            float yb[4] = {yb4.x, yb4.y, yb4.z, yb4.w};
#pragma unroll
            for (int i = 0; i < 4; ++i)
#pragma unroll
                for (int j = 0; j < 4; ++j) {
                    aA[i][j] = fmaf(xa[i], xb[j], aA[i][j]);
                    aB[i][j] = fmaf(ya[i], yb[j], aB[i][j]);
                }
        }
    }

    const size_t slabElems = (size_t)DIMS * DIMS;
    float* Adst = Abase + (useSlabs ? (size_t)s * slabElems : 0);
    float* Bdst = Bbase + (useSlabs ? (size_t)s * slabElems : 0);

#pragma unroll
    for (int i = 0; i < 4; ++i) {
        const int    ag    = ta * TILE + ca * 4 + i;
        const int    cbase = tb * TILE + cb * 4;
        const size_t idx   = (size_t)ag * DIMS + cbase;
        if (useSlabs) {
            *(float4*)(Adst + idx) = make_float4(aA[i][0], aA[i][1], aA[i][2], aA[i][3]);
            *(float4*)(Bdst + idx) = make_float4(aB[i][0], aB[i][1], aB[i][2], aB[i][3]);
        } else {
#pragma unroll
            for (int j = 0; j < 4; ++j) {
                atomicAdd(Adst + idx + j, aA[i][j]);
                atomicAdd(Bdst + idx + j, aB[i][j]);
            }
        }
    }
}

// sum_i <x_i,y_i> and sum_i <x_i,y_i>^2. One wave per 8 rows.
__global__ __launch_bounds__(256) void diag_kernel(
    const float* __restrict__ X, const float* __restrict__ Y,
    float* __restrict__ scal)
{
    const int tid  = threadIdx.x;
    const int lane = tid & 63;
    const int wave = blockIdx.x * 4 + (tid >> 6);   // 0..1023
    const float4* Xv = (const float4*)X;
    const float4* Yv = (const float4*)Y;

    float dsum = 0.f, dsq = 0.f;
    for (int r = 0; r < 8; ++r) {
        const int row  = wave * 8 + r;
        const int base = row * (DIMS / 4) + lane * 2;
        float4 x0 = Xv[base], x1 = Xv[base + 1];
        float4 y0 = Yv[base], y1 = Yv[base + 1];
        float v = x0.x * y0.x + x0.y * y0.y + x0.z * y0.z + x0.w * y0.w
                + x1.x * y1.x + x1.y * y1.y + x1.z * y1.z + x1.w * y1.w;
        for (int off = 32; off; off >>= 1) v += __shfl_xor(v, off);
        if (lane == 0) { dsum += v; dsq += v * v; }
    }
    if (lane == 0) {
        atomicAdd(scal + 0, dsum);
        atomicAdd(scal + 1, dsq);
    }
}

// S = sum_e (sum_s A_s[e]) * (sum_s B_s[e])
__global__ __launch_bounds__(256) void pass2_kernel(
    const float* __restrict__ Abase, const float* __restrict__ Bbase,
    float* __restrict__ scal, int nslab)
{
    const int tid = threadIdx.x;
    const int g   = blockIdx.x * 256 + tid;
    const size_t slabElems = (size_t)DIMS * DIMS;
    float local = 0.f;
    for (int e = g; e < (int)slabElems; e += 65536) {
        float a = 0.f, b = 0.f;
        for (int s2 = 0; s2 < nslab; ++s2) {
            a += Abase[(size_t)s2 * slabElems + e];
            b += Bbase[(size_t)s2 * slabElems + e];
        }
        local += a * b;
    }
    for (int off = 32; off; off >>= 1) local += __shfl_xor(local, off);
    __shared__ float red[4];
    if ((tid & 63) == 0) red[tid >> 6] = local;
    __syncthreads();
    if (tid == 0) atomicAdd(scal + 2, red[0] + red[1] + red[2] + red[3]);
}

__global__ void finalize_kernel(const float* __restrict__ scal,
                                float* __restrict__ out)
{
    if (threadIdx.x == 0 && blockIdx.x == 0) {
        const double S   = (double)scal[2];
        const double dsq = (double)scal[1];
        const double ds  = (double)scal[0];
        const double off = S - dsq;
        const double loss =
            off / ((double)N_ROWS * (double)(N_ROWS - 1)) - 2.0 * ds / (double)N_ROWS;
        out[0] = (float)loss;
    }
}

extern "C" void kernel_launch(void* const* d_in, const int* in_sizes, int n_in,
                              void* d_out, int out_size, void* d_ws, size_t ws_size,
                              hipStream_t stream)
{
    const float* X = (const float*)d_in[0];
    const float* Y = (const float*)d_in[1];
    float* out = (float*)d_out;
    float* wsf = (float*)d_ws;

    const size_t slabElems = (size_t)DIMS * DIMS;   // 262144
    const size_t hdr = 64;                           // 64 floats header (scalars)

    // Non-atomic per-k-split slabs if workspace is big enough (16.8 MB),
    // else atomic accumulation into a single slab pair (2.1 MB).
    const bool slabs = ws_size >= (hdr + 16 * slabElems) * sizeof(float);
    const int  nslab = slabs ? KSPLIT : 1;

    float* Abase = wsf + hdr;
    float* Bbase = Abase + (size_t)nslab * slabElems;

    // d_ws is poisoned to 0xAA before every timed call: zero what we accumulate into.
    hipMemsetAsync(d_ws, 0, hdr * sizeof(float), stream);
    if (!slabs) {
        hipMemsetAsync(Abase, 0, 2 * slabElems * sizeof(float), stream);
    }

    dim3 sg(64, KSPLIT);
    syrk_kernel<<<sg, NT, 0, stream>>>(X, Y, Abase, Bbase, slabs ? 1 : 0);
    diag_kernel<<<256, 256, 0, stream>>>(X, Y, wsf);
    pass2_kernel<<<256, 256, 0, stream>>>(Abase, Bbase, wsf, nslab);
    finalize_kernel<<<1, 64, 0, stream>>>(wsf, out);
}

// Round 2
// 168.319 us; speedup vs baseline: 1.4063x; 1.4063x over previous
//
#include <hip/hip_runtime.h>
#include <cstdint>

#define N_ROWS 8192
#define DIMS   512
#define NT     256

typedef unsigned short u16;
typedef __attribute__((ext_vector_type(8))) short s8v;          // 8 bf16 (4 VGPRs) MFMA A/B frag
typedef __attribute__((ext_vector_type(4))) float f4v;          // MFMA C/D frag
typedef __attribute__((ext_vector_type(8))) unsigned short u16x8;

// ---------------- bf16 helpers (manual RNE, no header friction) ----------------
__device__ __forceinline__ u16 f2bf(float f) {
    unsigned u = __float_as_uint(f);
    unsigned r = (u + 0x7fff + ((u >> 16) & 1)) >> 16;
    return (u16)r;
}
__device__ __forceinline__ float bf2f(u16 h) { return __uint_as_float(((unsigned)h) << 16); }

// async global->LDS, 16B per lane (CK-style casts through uintptr_t)
__device__ __forceinline__ void gl16(const void* g, void* l) {
    auto gp = (const __attribute__((address_space(1))) unsigned int*)(uintptr_t)g;
    auto lp = (__attribute__((address_space(3))) unsigned int*)(uintptr_t)l;
    __builtin_amdgcn_global_load_lds(gp, lp, 16, 0, 0);
}

// ================= convert+transpose: X[8192][512] f32 -> Xh,Xl [512][8192] bf16 =================
// grid: 2048 blocks (1024 tiles x 2 matrices), 256 threads. 64x64 tiles.
__global__ __launch_bounds__(NT) void convert_kernel(
    const float* __restrict__ X, const float* __restrict__ Y,
    u16* __restrict__ Xh, u16* __restrict__ Xl,
    u16* __restrict__ Yh, u16* __restrict__ Yl)
{
    const int b   = blockIdx.x;
    const int mat = b & 1;
    const int t2  = b >> 1;            // 0..1023
    const int nt  = t2 & 127;          // n-tile
    const int dt  = t2 >> 7;           // d-tile
    const float* S = mat ? Y : X;
    u16* Oh = mat ? Yh : Xh;
    u16* Ol = mat ? Yl : Xl;

    __shared__ float tile[64][65];     // +1 pad: transpose reads 2-way max (free)

    const int tid = threadIdx.x;
    const int c4 = tid & 15, rr = tid >> 4;
#pragma unroll
    for (int rp = 0; rp < 4; ++rp) {
        const int row = rp * 16 + rr;
        float4 v = *(const float4*)&S[(size_t)(nt * 64 + row) * DIMS + dt * 64 + c4 * 4];
        tile[row][c4 * 4 + 0] = v.x;
        tile[row][c4 * 4 + 1] = v.y;
        tile[row][c4 * 4 + 2] = v.z;
        tile[row][c4 * 4 + 3] = v.w;
    }
    __syncthreads();

    const int d = tid >> 2, ns = (tid & 3) * 16;
    u16x8 h0, h1, l0, l1;
#pragma unroll
    for (int i = 0; i < 8; ++i) {
        float x0 = tile[ns + i][d];
        u16 hh = f2bf(x0); h0[i] = hh; l0[i] = f2bf(x0 - bf2f(hh));
        float x1 = tile[ns + 8 + i][d];
        u16 hh1 = f2bf(x1); h1[i] = hh1; l1[i] = f2bf(x1 - bf2f(hh1));
    }
    const size_t ob = (size_t)(dt * 64 + d) * N_ROWS + nt * 64 + ns;
    *(u16x8*)&Oh[ob]     = h0;
    *(u16x8*)&Oh[ob + 8] = h1;
    *(u16x8*)&Ol[ob]     = l0;
    *(u16x8*)&Ol[ob + 8] = l1;
}

// ================= MFMA syrk: G = T^T-style NT gemm on transposed bf16 hi/lo =================
// grid: (16 tiles, 16 k-splits, 2 matrices), 256 threads (4 waves).
// Tile 128x128; per wave 64x64 = 4x4 mfma_f32_16x16x32_bf16 tiles; 3 split-products
// (hh, hl, lh) into the same fp32 acc. Epilogue: fp32 atomicAdd into slab.
__global__ __launch_bounds__(NT, 2) void syrk_mfma(
    const u16* __restrict__ Xh, const u16* __restrict__ Xl,
    const u16* __restrict__ Yh, const u16* __restrict__ Yl,
    float* __restrict__ Aslab, float* __restrict__ Bslab)
{
    __shared__ u16 smem[4 * 4096];     // 4 x [128][32] bf16 = 32 KB
    u16* Smh = smem;
    u16* Sml = smem + 4096;
    u16* Snh = smem + 8192;
    u16* Snl = smem + 12288;

    const int tid = threadIdx.x;
    const int bx = blockIdx.x, s = blockIdx.y, mat = blockIdx.z;
    const int m0 = (bx >> 2) * 128, n0 = (bx & 3) * 128;
    const u16* Th = mat ? Yh : Xh;
    const u16* Tl = mat ? Yl : Xl;

    const int w = tid >> 6, L = tid & 63;
    const int wm = (w >> 1) * 64, wn = (w & 1) * 64;
    const int lrow = L & 15, q = L >> 4;

    const int srow   = tid >> 2;          // staging row (0..63) within 64-row half
    const int schunk = (tid & 3) * 8;     // staging k-chunk (elems)

    f4v acc[4][4];
#pragma unroll
    for (int i = 0; i < 4; ++i)
#pragma unroll
        for (int j = 0; j < 4; ++j)
            acc[i][j] = (f4v){0.f, 0.f, 0.f, 0.f};

    const int kk0 = s * 512;

    for (int it = 0; it < 16; ++it) {
        const int kb = kk0 + it * 32;
        __syncthreads();
#pragma unroll
        for (int j = 0; j < 2; ++j) {
            const size_t rm = (size_t)(m0 + j * 64 + srow) * N_ROWS + kb + schunk;
            const size_t rn = (size_t)(n0 + j * 64 + srow) * N_ROWS + kb + schunk;
            const int dst = j * 2048 + tid * 8;
            gl16(Th + rm, Smh + dst);
            gl16(Tl + rm, Sml + dst);
            gl16(Th + rn, Snh + dst);
            gl16(Tl + rn, Snl + dst);
        }
        __syncthreads();

        s8v ah[4], al[4], bh[4], bl[4];
#pragma unroll
        for (int t = 0; t < 4; ++t) {
            const int ro = (wm + t * 16 + lrow) * 32 + q * 8;
            const int co = (wn + t * 16 + lrow) * 32 + q * 8;
            ah[t] = *(const s8v*)&Smh[ro];
            al[t] = *(const s8v*)&Sml[ro];
            bh[t] = *(const s8v*)&Snh[co];
            bl[t] = *(const s8v*)&Snl[co];
        }
#pragma unroll
        for (int ti = 0; ti < 4; ++ti)
#pragma unroll
            for (int tj = 0; tj < 4; ++tj) {
                acc[ti][tj] = __builtin_amdgcn_mfma_f32_16x16x32_bf16(ah[ti], bh[tj], acc[ti][tj], 0, 0, 0);
                acc[ti][tj] = __builtin_amdgcn_mfma_f32_16x16x32_bf16(ah[ti], bl[tj], acc[ti][tj], 0, 0, 0);
                acc[ti][tj] = __builtin_amdgcn_mfma_f32_16x16x32_bf16(al[ti], bh[tj], acc[ti][tj], 0, 0, 0);
            }
    }

    float* G = mat ? Bslab : Aslab;
#pragma unroll
    for (int ti = 0; ti < 4; ++ti)
#pragma unroll
        for (int tj = 0; tj < 4; ++tj)
#pragma unroll
            for (int r = 0; r < 4; ++r) {
                const int row = m0 + wm + ti * 16 + q * 4 + r;  // C/D: row=(lane>>4)*4+reg
                const int col = n0 + wn + tj * 16 + lrow;       //      col=lane&15
                atomicAdd(&G[row * DIMS + col], acc[ti][tj][r]);
            }
}

// ================= fp32 fallback syrk (round-1, proven) =================
#define TILE   64
#define KSPLIT 8
#define KCHUNK (N_ROWS / KSPLIT)
#define KB     16
__global__ __launch_bounds__(NT) void syrk_kernel(
    const float* __restrict__ X, const float* __restrict__ Y,
    float* __restrict__ Abase, float* __restrict__ Bbase, int useSlabs)
{
    const int tid = threadIdx.x;
    const int ta  = blockIdx.x >> 3;
    const int tb  = blockIdx.x & 7;
    const int s   = blockIdx.y;
    const int ca  = tid & 15;
    const int cb  = tid >> 4;

    __shared__ float4 sXA[KB * 16];
    __shared__ float4 sXB[KB * 16];
    __shared__ float4 sYA[KB * 16];
    __shared__ float4 sYB[KB * 16];

    const float4* Xv = (const float4*)X;
    const float4* Yv = (const float4*)Y;

    float aA[4][4] = {};
    float aB[4][4] = {};

    const int r0     = s * KCHUNK;
    const int rowOfT = tid >> 4;
    const int colOfT = tid & 15;

    for (int it = 0; it < KCHUNK / KB; ++it) {
        const int row  = r0 + it * KB + rowOfT;
        const int base = row * (DIMS / 4);
        __syncthreads();
        sXA[tid] = Xv[base + ta * 16 + colOfT];
        sXB[tid] = Xv[base + tb * 16 + colOfT];
        sYA[tid] = Yv[base + ta * 16 + colOfT];
        sYB[tid] = Yv[base + tb * 16 + colOfT];
        __syncthreads();
#pragma unroll
        for (int k = 0; k < KB; ++k) {
            float4 xa4 = sXA[k * 16 + ca];
            float4 xb4 = sXB[k * 16 + cb];
            float4 ya4 = sYA[k * 16 + ca];
            float4 yb4 = sYB[k * 16 + cb];
            float xa[4] = {xa4.x, xa4.y, xa4.z, xa4.w};
            float xb[4] = {xb4.x, xb4.y, xb4.z, xb4.w};
            float ya[4] = {ya4.x, ya4.y, ya4.z, ya4.w};
            float yb[4] = {yb4.x, yb4.y, yb4.z, yb4.w};
#pragma unroll
            for (int i = 0; i < 4; ++i)
#pragma unroll
                for (int j = 0; j < 4; ++j) {
                    aA[i][j] = fmaf(xa[i], xb[j], aA[i][j]);
                    aB[i][j] = fmaf(ya[i], yb[j], aB[i][j]);
                }
        }
    }

    const size_t slabElems = (size_t)DIMS * DIMS;
    float* Adst = Abase + (useSlabs ? (size_t)s * slabElems : 0);
    float* Bdst = Bbase + (useSlabs ? (size_t)s * slabElems : 0);

#pragma unroll
    for (int i = 0; i < 4; ++i) {
        const int    ag    = ta * TILE + ca * 4 + i;
        const int    cbase = tb * TILE + cb * 4;
        const size_t idx   = (size_t)ag * DIMS + cbase;
        if (useSlabs) {
            *(float4*)(Adst + idx) = make_float4(aA[i][0], aA[i][1], aA[i][2], aA[i][3]);
            *(float4*)(Bdst + idx) = make_float4(aB[i][0], aB[i][1], aB[i][2], aB[i][3]);
        } else {
#pragma unroll
            for (int j = 0; j < 4; ++j) {
                atomicAdd(Adst + idx + j, aA[i][j]);
                atomicAdd(Bdst + idx + j, aB[i][j]);
            }
        }
    }
}

// ================= diag: sum <x_i,y_i> and sum <x_i,y_i>^2 =================
__global__ __launch_bounds__(256) void diag_kernel(
    const float* __restrict__ X, const float* __restrict__ Y,
    float* __restrict__ scal)
{
    const int tid  = threadIdx.x;
    const int lane = tid & 63;
    const int wave = blockIdx.x * 4 + (tid >> 6);
    const float4* Xv = (const float4*)X;
    const float4* Yv = (const float4*)Y;

    float dsum = 0.f, dsq = 0.f;
    for (int r = 0; r < 8; ++r) {
        const int row  = wave * 8 + r;
        const int base = row * (DIMS / 4) + lane * 2;
        float4 x0 = Xv[base], x1 = Xv[base + 1];
        float4 y0 = Yv[base], y1 = Yv[base + 1];
        float v = x0.x * y0.x + x0.y * y0.y + x0.z * y0.z + x0.w * y0.w
                + x1.x * y1.x + x1.y * y1.y + x1.z * y1.z + x1.w * y1.w;
        for (int off = 32; off; off >>= 1) v += __shfl_xor(v, off);
        if (lane == 0) { dsum += v; dsq += v * v; }
    }
    if (lane == 0) {
        atomicAdd(scal + 0, dsum);
        atomicAdd(scal + 1, dsq);
    }
}

// ================= pass2: S = sum_e (sum_s A_s[e]) * (sum_s B_s[e]) =================
__global__ __launch_bounds__(256) void pass2_kernel(
    const float* __restrict__ Abase, const float* __restrict__ Bbase,
    float* __restrict__ scal, int nslab)
{
    const int tid = threadIdx.x;
    const int g   = blockIdx.x * 256 + tid;
    const size_t slabElems = (size_t)DIMS * DIMS;
    float local = 0.f;
    for (int e = g; e < (int)slabElems; e += 65536) {
        float a = 0.f, b = 0.f;
        for (int s2 = 0; s2 < nslab; ++s2) {
            a += Abase[(size_t)s2 * slabElems + e];
            b += Bbase[(size_t)s2 * slabElems + e];
        }
        local += a * b;
    }
    for (int off = 32; off; off >>= 1) local += __shfl_xor(local, off);
    __shared__ float red[4];
    if ((tid & 63) == 0) red[tid >> 6] = local;
    __syncthreads();
    if (tid == 0) atomicAdd(scal + 2, red[0] + red[1] + red[2] + red[3]);
}

__global__ void finalize_kernel(const float* __restrict__ scal,
                                float* __restrict__ out)
{
    if (threadIdx.x == 0 && blockIdx.x == 0) {
        const double S   = (double)scal[2];
        const double dsq = (double)scal[1];
        const double ds  = (double)scal[0];
        const double off = S - dsq;
        const double loss =
            off / ((double)N_ROWS * (double)(N_ROWS - 1)) - 2.0 * ds / (double)N_ROWS;
        out[0] = (float)loss;
    }
}

extern "C" void kernel_launch(void* const* d_in, const int* in_sizes, int n_in,
                              void* d_out, int out_size, void* d_ws, size_t ws_size,
                              hipStream_t stream)
{
    const float* X = (const float*)d_in[0];
    const float* Y = (const float*)d_in[1];
    float* out = (float*)d_out;
    float* wsf = (float*)d_ws;

    const size_t slabElems = (size_t)DIMS * DIMS;        // 262144
    const size_t hdr       = 64;                         // floats
    const size_t trElems   = (size_t)DIMS * N_ROWS;      // 4,194,304 bf16 per matrix
    // MFMA path layout: [hdr | Aslab | Bslab | Xh | Xl | Yh | Yl]
    const size_t mfmaBytes = (hdr + 2 * slabElems) * sizeof(float) + 4 * trElems * sizeof(u16);

    if (ws_size >= mfmaBytes) {
        float* Aslab = wsf + hdr;
        float* Bslab = Aslab + slabElems;
        u16* Xh = (u16*)((char*)d_ws + (hdr + 2 * slabElems) * sizeof(float));
        u16* Xl = Xh + trElems;
        u16* Yh = Xl + trElems;
        u16* Yl = Yh + trElems;

        hipMemsetAsync(d_ws, 0, (hdr + 2 * slabElems) * sizeof(float), stream);
        convert_kernel<<<2048, NT, 0, stream>>>(X, Y, Xh, Xl, Yh, Yl);
        syrk_mfma<<<dim3(16, 16, 2), NT, 0, stream>>>(Xh, Xl, Yh, Yl, Aslab, Bslab);
        diag_kernel<<<256, 256, 0, stream>>>(X, Y, wsf);
        pass2_kernel<<<256, 256, 0, stream>>>(Aslab, Bslab, wsf, 1);
        finalize_kernel<<<1, 64, 0, stream>>>(wsf, out);
    } else {
        // fp32 fallback (round-1 path)
        const bool slabs = ws_size >= (hdr + 16 * slabElems) * sizeof(float);
        const int  nslab = slabs ? KSPLIT : 1;
        float* Abase = wsf + hdr;
        float* Bbase = Abase + (size_t)nslab * slabElems;

        hipMemsetAsync(d_ws, 0, hdr * sizeof(float), stream);
        if (!slabs) hipMemsetAsync(Abase, 0, 2 * slabElems * sizeof(float), stream);

        dim3 sg(64, KSPLIT);
        syrk_kernel<<<sg, NT, 0, stream>>>(X, Y, Abase, Bbase, slabs ? 1 : 0);
        diag_kernel<<<256, 256, 0, stream>>>(X, Y, wsf);
        pass2_kernel<<<256, 256, 0, stream>>>(Abase, Bbase, wsf, nslab);
        finalize_kernel<<<1, 64, 0, stream>>>(wsf, out);
    }
}

// Round 3
// 144.535 us; speedup vs baseline: 1.6377x; 1.1646x over previous
//
#include <hip/hip_runtime.h>
#include <cstdint>

#define N_ROWS 8192
#define DIMS   512
#define NT     256
#define KSPLIT32 32
#define KCHUNK32 (N_ROWS / KSPLIT32)   // 256

typedef unsigned short u16;
typedef __attribute__((ext_vector_type(8))) short s8v;          // 8 bf16 MFMA A/B frag
typedef __attribute__((ext_vector_type(4))) float f4v;          // MFMA C/D frag
typedef __attribute__((ext_vector_type(8))) unsigned short u16x8;

__device__ __forceinline__ u16 f2bf(float f) {
    unsigned u = __float_as_uint(f);
    unsigned r = (u + 0x7fff + ((u >> 16) & 1)) >> 16;
    return (u16)r;
}
__device__ __forceinline__ float bf2f(u16 h) { return __uint_as_float(((unsigned)h) << 16); }

__device__ __forceinline__ void gl16(const void* g, void* l) {
    auto gp = (const __attribute__((address_space(1))) unsigned int*)(uintptr_t)g;
    auto lp = (__attribute__((address_space(3))) unsigned int*)(uintptr_t)l;
    __builtin_amdgcn_global_load_lds(gp, lp, 16, 0, 0);
}

// ============ convert + transpose + fused diag partials ============
// grid: 1024 blocks (nt 0..127, dt 0..7); each block handles BOTH X and Y tiles.
// Writes Xh/Xl/Yh/Yl [512][8192] bf16 and per-row partial <x_i,y_i> into diagDot.
__global__ __launch_bounds__(NT) void convert_diag(
    const float* __restrict__ X, const float* __restrict__ Y,
    u16* __restrict__ Xh, u16* __restrict__ Xl,
    u16* __restrict__ Yh, u16* __restrict__ Yl,
    float* __restrict__ diagDot, int doDiag)
{
    const int b  = blockIdx.x;
    const int nt = b & 127;
    const int dt = b >> 7;

    __shared__ float tx[64][65];
    __shared__ float ty[64][65];

    const int tid = threadIdx.x;
    const int c4 = tid & 15, rr = tid >> 4;
#pragma unroll
    for (int rp = 0; rp < 4; ++rp) {
        const int row = rp * 16 + rr;
        const size_t gbase = (size_t)(nt * 64 + row) * DIMS + dt * 64 + c4 * 4;
        float4 vx = *(const float4*)&X[gbase];
        float4 vy = *(const float4*)&Y[gbase];
        tx[row][c4 * 4 + 0] = vx.x; tx[row][c4 * 4 + 1] = vx.y;
        tx[row][c4 * 4 + 2] = vx.z; tx[row][c4 * 4 + 3] = vx.w;
        ty[row][c4 * 4 + 0] = vy.x; ty[row][c4 * 4 + 1] = vy.y;
        ty[row][c4 * 4 + 2] = vy.z; ty[row][c4 * 4 + 3] = vy.w;
        if (doDiag) {
            float d = vx.x * vy.x + vx.y * vy.y + vx.z * vy.z + vx.w * vy.w;
            d += __shfl_xor(d, 1); d += __shfl_xor(d, 2);
            d += __shfl_xor(d, 4); d += __shfl_xor(d, 8);
            if (c4 == 0) atomicAdd(&diagDot[nt * 64 + row], d);
        }
    }
    __syncthreads();

    const int d = tid >> 2, ns = (tid & 3) * 16;
    const size_t ob = (size_t)(dt * 64 + d) * N_ROWS + nt * 64 + ns;
#pragma unroll
    for (int mat = 0; mat < 2; ++mat) {
        float (*tp)[65] = mat ? ty : tx;
        u16* Oh = mat ? Yh : Xh;
        u16* Ol = mat ? Yl : Xl;
        u16x8 h0, h1, l0, l1;
#pragma unroll
        for (int i = 0; i < 8; ++i) {
            float x0 = tp[ns + i][d];
            u16 hh = f2bf(x0); h0[i] = hh; l0[i] = f2bf(x0 - bf2f(hh));
            float x1 = tp[ns + 8 + i][d];
            u16 hh1 = f2bf(x1); h1[i] = hh1; l1[i] = f2bf(x1 - bf2f(hh1));
        }
        *(u16x8*)&Oh[ob]     = h0;
        *(u16x8*)&Oh[ob + 8] = h1;
        *(u16x8*)&Ol[ob]     = l0;
        *(u16x8*)&Ol[ob + 8] = l1;
    }
}

// ============ symmetric MFMA syrk ============
// grid (KSPLIT32, 10, 2): x = k-split (XCD-major for L2 locality), y = upper tile
// pair of 4x4 grid of 128-tiles, z = matrix. 256 thr / 4 waves; 64x64 per wave.
// LDS stripes stored XOR-swizzled: elem (row, q*8+e) at row*32 + (q^((row>>1)&3))*8 + e
// -> ds_read_b128 frags tile all 8 bank granules (2 lanes each = conflict-free).
__global__ __launch_bounds__(NT) void syrk_mfma(
    const u16* __restrict__ Xh, const u16* __restrict__ Xl,
    const u16* __restrict__ Yh, const u16* __restrict__ Yl,
    float* __restrict__ Aslab, float* __restrict__ Bslab)
{
    __shared__ u16 smem[4 * 4096];     // Smh, Sml, Snh, Snl: [128][32] each, 32 KB
    u16* Smh = smem;
    u16* Sml = smem + 4096;
    u16* Snh = smem + 8192;
    u16* Snl = smem + 12288;

    const int tid = threadIdx.x;
    const int s = blockIdx.x, p = blockIdx.y, mat = blockIdx.z;
    const int ti_t[10] = {0,0,0,0,1,1,1,2,2,3};
    const int tj_t[10] = {0,1,2,3,1,2,3,2,3,3};
    const int m0 = ti_t[p] * 128, n0 = tj_t[p] * 128;
    const u16* Th = mat ? Yh : Xh;
    const u16* Tl = mat ? Yl : Xl;

    const int w = tid >> 6, L = tid & 63;
    const int wm = (w >> 1) * 64, wn = (w & 1) * 64;
    const int lrow = L & 15, q = L >> 4;

    // staging: thread tid, round j covers row = j*64 + (tid>>2), stored slot tid&3
    const int srowl = tid >> 2;
    const int sq    = (tid & 3) ^ ((srowl >> 1) & 3);   // logical k-chunk this lane fetches

    f4v acc[4][4];
#pragma unroll
    for (int i = 0; i < 4; ++i)
#pragma unroll
        for (int j = 0; j < 4; ++j)
            acc[i][j] = (f4v){0.f, 0.f, 0.f, 0.f};

    const int kk0 = s * KCHUNK32;

    for (int it = 0; it < KCHUNK32 / 32; ++it) {
        const int kb = kk0 + it * 32;
        __syncthreads();
#pragma unroll
        for (int j = 0; j < 2; ++j) {
            const int row = j * 64 + srowl;
            const size_t rm = (size_t)(m0 + row) * N_ROWS + kb + sq * 8;
            const size_t rn = (size_t)(n0 + row) * N_ROWS + kb + sq * 8;
            const int dst = j * 2048 + tid * 8;
            gl16(Th + rm, Smh + dst);
            gl16(Tl + rm, Sml + dst);
            gl16(Th + rn, Snh + dst);
            gl16(Tl + rn, Snl + dst);
        }
        __syncthreads();

        s8v ah[4], al[4], bh[4], bl[4];
#pragma unroll
        for (int t = 0; t < 4; ++t) {
            const int rowA = wm + t * 16 + lrow;
            const int rowB = wn + t * 16 + lrow;
            const int ro = rowA * 32 + ((q ^ ((rowA >> 1) & 3)) * 8);
            const int co = rowB * 32 + ((q ^ ((rowB >> 1) & 3)) * 8);
            ah[t] = *(const s8v*)&Smh[ro];
            al[t] = *(const s8v*)&Sml[ro];
            bh[t] = *(const s8v*)&Snh[co];
            bl[t] = *(const s8v*)&Snl[co];
        }
#pragma unroll
        for (int ti = 0; ti < 4; ++ti)
#pragma unroll
            for (int tj = 0; tj < 4; ++tj) {
                acc[ti][tj] = __builtin_amdgcn_mfma_f32_16x16x32_bf16(ah[ti], bh[tj], acc[ti][tj], 0, 0, 0);
                acc[ti][tj] = __builtin_amdgcn_mfma_f32_16x16x32_bf16(ah[ti], bl[tj], acc[ti][tj], 0, 0, 0);
                acc[ti][tj] = __builtin_amdgcn_mfma_f32_16x16x32_bf16(al[ti], bh[tj], acc[ti][tj], 0, 0, 0);
            }
    }

    float* G = mat ? Bslab : Aslab;
#pragma unroll
    for (int ti = 0; ti < 4; ++ti)
#pragma unroll
        for (int tj = 0; tj < 4; ++tj)
#pragma unroll
            for (int r = 0; r < 4; ++r) {
                const int row = m0 + wm + ti * 16 + q * 4 + r;
                const int col = n0 + wn + tj * 16 + lrow;
                atomicAdd(&G[row * DIMS + col], acc[ti][tj][r]);
            }
}

// ============ pass2: weighted <A,B> over upper tiles + diag reduce ============
__global__ __launch_bounds__(256) void pass2_sym(
    const float* __restrict__ Aslab, const float* __restrict__ Bslab,
    const float* __restrict__ diagDot, float* __restrict__ scal)
{
    const int tid = threadIdx.x;
    const int g   = blockIdx.x * 256 + tid;
    float sS = 0.f, sD = 0.f, sD2 = 0.f;
#pragma unroll
    for (int e = g; e < DIMS * DIMS; e += 65536) {
        const int r = e >> 9, c = e & 511;
        const float w = ((r >> 7) == (c >> 7)) ? 1.f : 2.f;
        sS += w * Aslab[e] * Bslab[e];
    }
    if (diagDot && g < N_ROWS) {
        float d = diagDot[g];
        sD = d; sD2 = d * d;
    }
    for (int off = 32; off; off >>= 1) {
        sS  += __shfl_xor(sS,  off);
        sD  += __shfl_xor(sD,  off);
        sD2 += __shfl_xor(sD2, off);
    }
    __shared__ float red[3][4];
    if ((tid & 63) == 0) {
        red[0][tid >> 6] = sS; red[1][tid >> 6] = sD; red[2][tid >> 6] = sD2;
    }
    __syncthreads();
    if (tid == 0) {
        atomicAdd(scal + 2, red[0][0] + red[0][1] + red[0][2] + red[0][3]);
        if (diagDot) {
            atomicAdd(scal + 0, red[1][0] + red[1][1] + red[1][2] + red[1][3]);
            atomicAdd(scal + 1, red[2][0] + red[2][1] + red[2][2] + red[2][3]);
        }
    }
}

// ============ standalone diag (mid/fp32 fallback) ============
__global__ __launch_bounds__(256) void diag_kernel(
    const float* __restrict__ X, const float* __restrict__ Y,
    float* __restrict__ scal)
{
    const int tid  = threadIdx.x;
    const int lane = tid & 63;
    const int wave = blockIdx.x * 4 + (tid >> 6);
    const float4* Xv = (const float4*)X;
    const float4* Yv = (const float4*)Y;

    float dsum = 0.f, dsq = 0.f;
    for (int r = 0; r < 8; ++r) {
        const int row  = wave * 8 + r;
        const int base = row * (DIMS / 4) + lane * 2;
        float4 x0 = Xv[base], x1 = Xv[base + 1];
        float4 y0 = Yv[base], y1 = Yv[base + 1];
        float v = x0.x * y0.x + x0.y * y0.y + x0.z * y0.z + x0.w * y0.w
                + x1.x * y1.x + x1.y * y1.y + x1.z * y1.z + x1.w * y1.w;
        for (int off = 32; off; off >>= 1) v += __shfl_xor(v, off);
        if (lane == 0) { dsum += v; dsq += v * v; }
    }
    if (lane == 0) {
        atomicAdd(scal + 0, dsum);
        atomicAdd(scal + 1, dsq);
    }
}

// ============ fp32 fallback syrk (round-1, proven) ============
#define TILE   64
#define KSPLIT 8
#define KCHUNK (N_ROWS / KSPLIT)
#define KB     16
__global__ __launch_bounds__(NT) void syrk_kernel(
    const float* __restrict__ X, const float* __restrict__ Y,
    float* __restrict__ Abase, float* __restrict__ Bbase, int useSlabs)
{
    const int tid = threadIdx.x;
    const int ta  = blockIdx.x >> 3;
    const int tb  = blockIdx.x & 7;
    const int s   = blockIdx.y;
    const int ca  = tid & 15;
    const int cb  = tid >> 4;

    __shared__ float4 sXA[KB * 16];
    __shared__ float4 sXB[KB * 16];
    __shared__ float4 sYA[KB * 16];
    __shared__ float4 sYB[KB * 16];

    const float4* Xv = (const float4*)X;
    const float4* Yv = (const float4*)Y;

    float aA[4][4] = {};
    float aB[4][4] = {};

    const int r0     = s * KCHUNK;
    const int rowOfT = tid >> 4;
    const int colOfT = tid & 15;

    for (int it = 0; it < KCHUNK / KB; ++it) {
        const int row  = r0 + it * KB + rowOfT;
        const int base = row * (DIMS / 4);
        __syncthreads();
        sXA[tid] = Xv[base + ta * 16 + colOfT];
        sXB[tid] = Xv[base + tb * 16 + colOfT];
        sYA[tid] = Yv[base + ta * 16 + colOfT];
        sYB[tid] = Yv[base + tb * 16 + colOfT];
        __syncthreads();
#pragma unroll
        for (int k = 0; k < KB; ++k) {
            float4 xa4 = sXA[k * 16 + ca];
            float4 xb4 = sXB[k * 16 + cb];
            float4 ya4 = sYA[k * 16 + ca];
            float4 yb4 = sYB[k * 16 + cb];
            float xa[4] = {xa4.x, xa4.y, xa4.z, xa4.w};
            float xb[4] = {xb4.x, xb4.y, xb4.z, xb4.w};
            float ya[4] = {ya4.x, ya4.y, ya4.z, ya4.w};
            float yb[4] = {yb4.x, yb4.y, yb4.z, yb4.w};
#pragma unroll
            for (int i = 0; i < 4; ++i)
#pragma unroll
                for (int j = 0; j < 4; ++j) {
                    aA[i][j] = fmaf(xa[i], xb[j], aA[i][j]);
                    aB[i][j] = fmaf(ya[i], yb[j], aB[i][j]);
                }
        }
    }

    const size_t slabElems = (size_t)DIMS * DIMS;
    float* Adst = Abase + (useSlabs ? (size_t)s * slabElems : 0);
    float* Bdst = Bbase + (useSlabs ? (size_t)s * slabElems : 0);

#pragma unroll
    for (int i = 0; i < 4; ++i) {
        const int    ag    = ta * TILE + ca * 4 + i;
        const int    cbase = tb * TILE + cb * 4;
        const size_t idx   = (size_t)ag * DIMS + cbase;
        if (useSlabs) {
            *(float4*)(Adst + idx) = make_float4(aA[i][0], aA[i][1], aA[i][2], aA[i][3]);
            *(float4*)(Bdst + idx) = make_float4(aB[i][0], aB[i][1], aB[i][2], aB[i][3]);
        } else {
#pragma unroll
            for (int j = 0; j < 4; ++j) {
                atomicAdd(Adst + idx + j, aA[i][j]);
                atomicAdd(Bdst + idx + j, aB[i][j]);
            }
        }
    }
}

__global__ __launch_bounds__(256) void pass2_kernel(
    const float* __restrict__ Abase, const float* __restrict__ Bbase,
    float* __restrict__ scal, int nslab)
{
    const int tid = threadIdx.x;
    const int g   = blockIdx.x * 256 + tid;
    const size_t slabElems = (size_t)DIMS * DIMS;
    float local = 0.f;
    for (int e = g; e < (int)slabElems; e += 65536) {
        float a = 0.f, b = 0.f;
        for (int s2 = 0; s2 < nslab; ++s2) {
            a += Abase[(size_t)s2 * slabElems + e];
            b += Bbase[(size_t)s2 * slabElems + e];
        }
        local += a * b;
    }
    for (int off = 32; off; off >>= 1) local += __shfl_xor(local, off);
    __shared__ float red[4];
    if ((tid & 63) == 0) red[tid >> 6] = local;
    __syncthreads();
    if (tid == 0) atomicAdd(scal + 2, red[0] + red[1] + red[2] + red[3]);
}

__global__ void finalize_kernel(const float* __restrict__ scal,
                                float* __restrict__ out)
{
    if (threadIdx.x == 0 && blockIdx.x == 0) {
        const double S   = (double)scal[2];
        const double dsq = (double)scal[1];
        const double ds  = (double)scal[0];
        const double off = S - dsq;
        const double loss =
            off / ((double)N_ROWS * (double)(N_ROWS - 1)) - 2.0 * ds / (double)N_ROWS;
        out[0] = (float)loss;
    }
}

extern "C" void kernel_launch(void* const* d_in, const int* in_sizes, int n_in,
                              void* d_out, int out_size, void* d_ws, size_t ws_size,
                              hipStream_t stream)
{
    const float* X = (const float*)d_in[0];
    const float* Y = (const float*)d_in[1];
    float* out = (float*)d_out;
    float* wsf = (float*)d_ws;

    const size_t slabElems = (size_t)DIMS * DIMS;        // 262144
    const size_t hdr       = 64;                         // floats
    const size_t trElems   = (size_t)DIMS * N_ROWS;      // 4,194,304 bf16/matrix

    // Full layout: [hdr | diagDot(8192) | Aslab | Bslab | Xh | Xl | Yh | Yl]
    const size_t fullBytes = (hdr + N_ROWS + 2 * slabElems) * sizeof(float) + 4 * trElems * sizeof(u16);
    // Mid layout (no diagDot): [hdr | Aslab | Bslab | Xh | Xl | Yh | Yl]
    const size_t midBytes  = (hdr + 2 * slabElems) * sizeof(float) + 4 * trElems * sizeof(u16);

    if (ws_size >= midBytes) {
        const bool full = ws_size >= fullBytes;
        float* diagDot = full ? (wsf + hdr) : nullptr;
        float* Aslab   = wsf + hdr + (full ? N_ROWS : 0);
        float* Bslab   = Aslab + slabElems;
        u16* Xh = (u16*)(Bslab + slabElems);
        u16* Xl = Xh + trElems;
        u16* Yh = Xl + trElems;
        u16* Yl = Yh + trElems;

        const size_t zeroBytes = (hdr + (full ? N_ROWS : 0) + 2 * slabElems) * sizeof(float);
        hipMemsetAsync(d_ws, 0, zeroBytes, stream);

        convert_diag<<<1024, NT, 0, stream>>>(X, Y, Xh, Xl, Yh, Yl, diagDot, full ? 1 : 0);
        syrk_mfma<<<dim3(KSPLIT32, 10, 2), NT, 0, stream>>>(Xh, Xl, Yh, Yl, Aslab, Bslab);
        if (!full) diag_kernel<<<256, 256, 0, stream>>>(X, Y, wsf);
        pass2_sym<<<256, 256, 0, stream>>>(Aslab, Bslab, diagDot, wsf);
        finalize_kernel<<<1, 64, 0, stream>>>(wsf, out);
    } else {
        const bool slabs = ws_size >= (hdr + 16 * slabElems) * sizeof(float);
        const int  nslab = slabs ? KSPLIT : 1;
        float* Abase = wsf + hdr;
        float* Bbase = Abase + (size_t)nslab * slabElems;

        hipMemsetAsync(d_ws, 0, hdr * sizeof(float), stream);
        if (!slabs) hipMemsetAsync(Abase, 0, 2 * slabElems * sizeof(float), stream);

        dim3 sg(64, KSPLIT);
        syrk_kernel<<<sg, NT, 0, stream>>>(X, Y, Abase, Bbase, slabs ? 1 : 0);
        diag_kernel<<<256, 256, 0, stream>>>(X, Y, wsf);
        pass2_kernel<<<256, 256, 0, stream>>>(Abase, Bbase, wsf, nslab);
        finalize_kernel<<<1, 64, 0, stream>>>(wsf, out);
    }
}

// Round 4
// 108.265 us; speedup vs baseline: 2.1863x; 1.3350x over previous
//
#include <hip/hip_runtime.h>
#include <cstdint>

#define N_ROWS 8192
#define DIMS   512
#define NT     256

typedef unsigned short u16;
typedef __attribute__((ext_vector_type(8))) short s8v;            // 8 bf16 MFMA A/B frag
typedef __attribute__((ext_vector_type(4))) float f4v;            // MFMA C/D frag
typedef __attribute__((ext_vector_type(8))) unsigned short u16x8;

__device__ __forceinline__ u16 f2bf(float f) {
    unsigned u = __float_as_uint(f);
    unsigned r = (u + 0x7fff + ((u >> 16) & 1)) >> 16;
    return (u16)r;
}
__device__ __forceinline__ float bf2f(u16 h) { return __uint_as_float(((unsigned)h) << 16); }

__device__ __forceinline__ void gl16(const void* g, void* l) {
    auto gp = (const __attribute__((address_space(1))) unsigned int*)(uintptr_t)g;
    auto lp = (__attribute__((address_space(3))) unsigned int*)(uintptr_t)l;
    __builtin_amdgcn_global_load_lds(gp, lp, 16, 0, 0);
}

// ============ convert + transpose (hi only) + fused diag partials ============
// grid: 1024 blocks (nt 0..127, dt 0..7). Writes Xh/Yh [512][8192] bf16 and
// per-row partial <x_i,y_i> into diagDot (fp32 exact).
__global__ __launch_bounds__(NT) void convert_diag(
    const float* __restrict__ X, const float* __restrict__ Y,
    u16* __restrict__ Xh, u16* __restrict__ Yh,
    float* __restrict__ diagDot)
{
    const int b  = blockIdx.x;
    const int nt = b & 127;
    const int dt = b >> 7;

    __shared__ float tx[64][65];
    __shared__ float ty[64][65];

    const int tid = threadIdx.x;
    const int c4 = tid & 15, rr = tid >> 4;
#pragma unroll
    for (int rp = 0; rp < 4; ++rp) {
        const int row = rp * 16 + rr;
        const size_t gbase = (size_t)(nt * 64 + row) * DIMS + dt * 64 + c4 * 4;
        float4 vx = *(const float4*)&X[gbase];
        float4 vy = *(const float4*)&Y[gbase];
        tx[row][c4 * 4 + 0] = vx.x; tx[row][c4 * 4 + 1] = vx.y;
        tx[row][c4 * 4 + 2] = vx.z; tx[row][c4 * 4 + 3] = vx.w;
        ty[row][c4 * 4 + 0] = vy.x; ty[row][c4 * 4 + 1] = vy.y;
        ty[row][c4 * 4 + 2] = vy.z; ty[row][c4 * 4 + 3] = vy.w;
        float d = vx.x * vy.x + vx.y * vy.y + vx.z * vy.z + vx.w * vy.w;
        d += __shfl_xor(d, 1); d += __shfl_xor(d, 2);
        d += __shfl_xor(d, 4); d += __shfl_xor(d, 8);
        if (c4 == 0) atomicAdd(&diagDot[nt * 64 + row], d);
    }
    __syncthreads();

    const int d = tid >> 2, ns = (tid & 3) * 16;
    const size_t ob = (size_t)(dt * 64 + d) * N_ROWS + nt * 64 + ns;
#pragma unroll
    for (int mat = 0; mat < 2; ++mat) {
        float (*tp)[65] = mat ? ty : tx;
        u16* Oh = mat ? Yh : Xh;
        u16x8 h0, h1;
#pragma unroll
        for (int i = 0; i < 8; ++i) {
            h0[i] = f2bf(tp[ns + i][d]);
            h1[i] = f2bf(tp[ns + 8 + i][d]);
        }
        *(u16x8*)&Oh[ob]     = h0;
        *(u16x8*)&Oh[ob + 8] = h1;
    }
}

// ============ symmetric bf16 syrk, double-buffered LDS, no atomics ============
// grid (nsplit, 10, 2): x = k-split, y = upper tile pair, z = matrix.
// BK=64 per stage, 2 stages (64 KB LDS). Per wave 64x64 = 4x4 16x16x32 tiles.
// LDS layout [row][64] with chunk XOR swizzle: logical chunk c stored at c^(row&7).
// Epilogue mode 0: bf16 store to private slab slot; mode 1: fp32 atomicAdd.
__global__ __launch_bounds__(NT) void syrk_bf16(
    const u16* __restrict__ Xh, const u16* __restrict__ Yh,
    u16* __restrict__ slabs, float* __restrict__ Aslab, float* __restrict__ Bslab,
    int kchunk, int mode)
{
    __shared__ u16 smem[2 * 2 * 8192];   // [stage][stripe][128*64] = 64 KB

    const int tid = threadIdx.x;
    const int s = blockIdx.x, p = blockIdx.y, mat = blockIdx.z;
    const int ti_t[10] = {0,0,0,0,1,1,1,2,2,3};
    const int tj_t[10] = {0,1,2,3,1,2,3,2,3,3};
    const int m0 = ti_t[p] * 128, n0 = tj_t[p] * 128;
    const u16* Th = mat ? Yh : Xh;

    const int w = tid >> 6, L = tid & 63;
    const int wm = (w >> 1) * 64, wn = (w & 1) * 64;
    const int lrow = L & 15, q = L >> 4;

    f4v acc[4][4];
#pragma unroll
    for (int i = 0; i < 4; ++i)
#pragma unroll
        for (int j = 0; j < 4; ++j)
            acc[i][j] = (f4v){0.f, 0.f, 0.f, 0.f};

    const int kk0 = s * kchunk;
    const int nIter = kchunk / 64;

    // stage loader: physical slot = j*256+tid (gl16 needs lane-contiguous LDS),
    // row = slot>>3, phys chunk pc = slot&7, logical chunk c = pc ^ (row&7).
    auto loadStage = [&](int buf, int kb) {
        u16* dA = smem + buf * 16384;
        u16* dB = dA + 8192;
#pragma unroll
        for (int j = 0; j < 4; ++j) {
            const int slot = j * 256 + tid;
            const int row  = slot >> 3;
            const int c    = (slot & 7) ^ (row & 7);
            gl16(Th + (size_t)(m0 + row) * N_ROWS + kb + c * 8, dA + slot * 8);
            gl16(Th + (size_t)(n0 + row) * N_ROWS + kb + c * 8, dB + slot * 8);
        }
    };

    loadStage(0, kk0);

    for (int it = 0; it < nIter; ++it) {
        __syncthreads();                       // drains my stage-it gl16s, syncs block
        if (it + 1 < nIter) loadStage((it + 1) & 1, kk0 + (it + 1) * 64);

        const u16* SA = smem + (it & 1) * 16384;
        const u16* SB = SA + 8192;
#pragma unroll
        for (int ks = 0; ks < 2; ++ks) {
            s8v a[4], b[4];
#pragma unroll
            for (int t = 0; t < 4; ++t) {
                const int rowA = wm + t * 16 + lrow;
                const int rowB = wn + t * 16 + lrow;
                const int pA = (ks * 4 + q) ^ (rowA & 7);
                const int pB = (ks * 4 + q) ^ (rowB & 7);
                a[t] = *(const s8v*)&SA[rowA * 64 + pA * 8];
                b[t] = *(const s8v*)&SB[rowB * 64 + pB * 8];
            }
#pragma unroll
            for (int ti2 = 0; ti2 < 4; ++ti2)
#pragma unroll
                for (int tj2 = 0; tj2 < 4; ++tj2)
                    acc[ti2][tj2] = __builtin_amdgcn_mfma_f32_16x16x32_bf16(
                        a[ti2], b[tj2], acc[ti2][tj2], 0, 0, 0);
        }
        // next iteration's __syncthreads separates this compute from load(it+2)
    }

    if (mode == 0) {
        u16* dst = slabs + ((size_t)(s * 2 + mat) * 10 + p) * 16384;
#pragma unroll
        for (int ti2 = 0; ti2 < 4; ++ti2)
#pragma unroll
            for (int tj2 = 0; tj2 < 4; ++tj2)
#pragma unroll
                for (int r = 0; r < 4; ++r) {
                    const int rl = wm + ti2 * 16 + q * 4 + r;
                    const int cl = wn + tj2 * 16 + lrow;
                    dst[rl * 128 + cl] = f2bf(acc[ti2][tj2][r]);
                }
    } else {
        float* G = mat ? Bslab : Aslab;
#pragma unroll
        for (int ti2 = 0; ti2 < 4; ++ti2)
#pragma unroll
            for (int tj2 = 0; tj2 < 4; ++tj2)
#pragma unroll
                for (int r = 0; r < 4; ++r) {
                    const int row = m0 + wm + ti2 * 16 + q * 4 + r;
                    const int col = n0 + wn + tj2 * 16 + lrow;
                    atomicAdd(&G[row * DIMS + col], acc[ti2][tj2][r]);
                }
    }
}

// ============ pass2 (packed bf16 slabs): S = sum_p w_p <sum_s A, sum_s B> ============
// grid 80 blocks x 256 = 20480 threads; each owns 8 consecutive elems of one tile.
__global__ __launch_bounds__(256) void pass2_packed(
    const u16* __restrict__ slabs, const float* __restrict__ diagDot,
    float* __restrict__ scal, int nsplit)
{
    const int tid = threadIdx.x;
    const int g   = blockIdx.x * 256 + tid;        // 0..20479
    float sS = 0.f, sD = 0.f, sD2 = 0.f;

    const int p  = g >> 11;                        // tile pair 0..9
    const int e8 = (g & 2047) * 8;
    const float wp = ((p == 0) | (p == 4) | (p == 7) | (p == 9)) ? 1.f : 2.f;
    float a[8] = {}, b[8] = {};
    for (int s = 0; s < nsplit; ++s) {
        u16x8 va = *(const u16x8*)&slabs[((size_t)(s * 2 + 0) * 10 + p) * 16384 + e8];
        u16x8 vb = *(const u16x8*)&slabs[((size_t)(s * 2 + 1) * 10 + p) * 16384 + e8];
#pragma unroll
        for (int i = 0; i < 8; ++i) { a[i] += bf2f(va[i]); b[i] += bf2f(vb[i]); }
    }
#pragma unroll
    for (int i = 0; i < 8; ++i) sS += a[i] * b[i];
    sS *= wp;

    if (g < N_ROWS) { const float d = diagDot[g]; sD = d; sD2 = d * d; }

    for (int off = 32; off; off >>= 1) {
        sS  += __shfl_xor(sS,  off);
        sD  += __shfl_xor(sD,  off);
        sD2 += __shfl_xor(sD2, off);
    }
    __shared__ float red[3][4];
    if ((tid & 63) == 0) {
        red[0][tid >> 6] = sS; red[1][tid >> 6] = sD; red[2][tid >> 6] = sD2;
    }
    __syncthreads();
    if (tid == 0) {
        atomicAdd(scal + 2, red[0][0] + red[0][1] + red[0][2] + red[0][3]);
        atomicAdd(scal + 0, red[1][0] + red[1][1] + red[1][2] + red[1][3]);
        atomicAdd(scal + 1, red[2][0] + red[2][1] + red[2][2] + red[2][3]);
    }
}

// ============ pass2 for atomic-slab mode (upper tiles, weight 2 off-diag) ============
__global__ __launch_bounds__(256) void pass2_sym(
    const float* __restrict__ Aslab, const float* __restrict__ Bslab,
    const float* __restrict__ diagDot, float* __restrict__ scal)
{
    const int tid = threadIdx.x;
    const int g   = blockIdx.x * 256 + tid;
    float sS = 0.f, sD = 0.f, sD2 = 0.f;
    for (int e = g; e < DIMS * DIMS; e += 65536) {
        const int r = e >> 9, c = e & 511;
        const float w = ((r >> 7) == (c >> 7)) ? 1.f : 2.f;
        sS += w * Aslab[e] * Bslab[e];
    }
    if (g < N_ROWS) { const float d = diagDot[g]; sD = d; sD2 = d * d; }
    for (int off = 32; off; off >>= 1) {
        sS  += __shfl_xor(sS,  off);
        sD  += __shfl_xor(sD,  off);
        sD2 += __shfl_xor(sD2, off);
    }
    __shared__ float red[3][4];
    if ((tid & 63) == 0) {
        red[0][tid >> 6] = sS; red[1][tid >> 6] = sD; red[2][tid >> 6] = sD2;
    }
    __syncthreads();
    if (tid == 0) {
        atomicAdd(scal + 2, red[0][0] + red[0][1] + red[0][2] + red[0][3]);
        atomicAdd(scal + 0, red[1][0] + red[1][1] + red[1][2] + red[1][3]);
        atomicAdd(scal + 1, red[2][0] + red[2][1] + red[2][2] + red[2][3]);
    }
}

// ============ fp32 fallback syrk (round-1, proven) ============
#define TILE   64
#define KSPLIT 8
#define KCHUNK (N_ROWS / KSPLIT)
#define KB     16
__global__ __launch_bounds__(NT) void syrk_kernel(
    const float* __restrict__ X, const float* __restrict__ Y,
    float* __restrict__ Abase, float* __restrict__ Bbase, int useSlabs)
{
    const int tid = threadIdx.x;
    const int ta  = blockIdx.x >> 3;
    const int tb  = blockIdx.x & 7;
    const int s   = blockIdx.y;
    const int ca  = tid & 15;
    const int cb  = tid >> 4;

    __shared__ float4 sXA[KB * 16];
    __shared__ float4 sXB[KB * 16];
    __shared__ float4 sYA[KB * 16];
    __shared__ float4 sYB[KB * 16];

    const float4* Xv = (const float4*)X;
    const float4* Yv = (const float4*)Y;

    float aA[4][4] = {};
    float aB[4][4] = {};

    const int r0     = s * KCHUNK;
    const int rowOfT = tid >> 4;
    const int colOfT = tid & 15;

    for (int it = 0; it < KCHUNK / KB; ++it) {
        const int row  = r0 + it * KB + rowOfT;
        const int base = row * (DIMS / 4);
        __syncthreads();
        sXA[tid] = Xv[base + ta * 16 + colOfT];
        sXB[tid] = Xv[base + tb * 16 + colOfT];
        sYA[tid] = Yv[base + ta * 16 + colOfT];
        sYB[tid] = Yv[base + tb * 16 + colOfT];
        __syncthreads();
#pragma unroll
        for (int k = 0; k < KB; ++k) {
            float4 xa4 = sXA[k * 16 + ca];
            float4 xb4 = sXB[k * 16 + cb];
            float4 ya4 = sYA[k * 16 + ca];
            float4 yb4 = sYB[k * 16 + cb];
            float xa[4] = {xa4.x, xa4.y, xa4.z, xa4.w};
            float xb[4] = {xb4.x, xb4.y, xb4.z, xb4.w};
            float ya[4] = {ya4.x, ya4.y, ya4.z, ya4.w};
            float yb[4] = {yb4.x, yb4.y, yb4.z, yb4.w};
#pragma unroll
            for (int i = 0; i < 4; ++i)
#pragma unroll
                for (int j = 0; j < 4; ++j) {
                    aA[i][j] = fmaf(xa[i], xb[j], aA[i][j]);
                    aB[i][j] = fmaf(ya[i], yb[j], aB[i][j]);
                }
        }
    }

    const size_t slabElems = (size_t)DIMS * DIMS;
    float* Adst = Abase + (useSlabs ? (size_t)s * slabElems : 0);
    float* Bdst = Bbase + (useSlabs ? (size_t)s * slabElems : 0);

#pragma unroll
    for (int i = 0; i < 4; ++i) {
        const int    ag    = ta * TILE + ca * 4 + i;
        const int    cbase = tb * TILE + cb * 4;
        const size_t idx   = (size_t)ag * DIMS + cbase;
        if (useSlabs) {
            *(float4*)(Adst + idx) = make_float4(aA[i][0], aA[i][1], aA[i][2], aA[i][3]);
            *(float4*)(Bdst + idx) = make_float4(aB[i][0], aB[i][1], aB[i][2], aB[i][3]);
        } else {
#pragma unroll
            for (int j = 0; j < 4; ++j) {
                atomicAdd(Adst + idx + j, aA[i][j]);
                atomicAdd(Bdst + idx + j, aB[i][j]);
            }
        }
    }
}

__global__ __launch_bounds__(256) void diag_kernel(
    const float* __restrict__ X, const float* __restrict__ Y,
    float* __restrict__ scal)
{
    const int tid  = threadIdx.x;
    const int lane = tid & 63;
    const int wave = blockIdx.x * 4 + (tid >> 6);
    const float4* Xv = (const float4*)X;
    const float4* Yv = (const float4*)Y;

    float dsum = 0.f, dsq = 0.f;
    for (int r = 0; r < 8; ++r) {
        const int row  = wave * 8 + r;
        const int base = row * (DIMS / 4) + lane * 2;
        float4 x0 = Xv[base], x1 = Xv[base + 1];
        float4 y0 = Yv[base], y1 = Yv[base + 1];
        float v = x0.x * y0.x + x0.y * y0.y + x0.z * y0.z + x0.w * y0.w
                + x1.x * y1.x + x1.y * y1.y + x1.z * y1.z + x1.w * y1.w;
        for (int off = 32; off; off >>= 1) v += __shfl_xor(v, off);
        if (lane == 0) { dsum += v; dsq += v * v; }
    }
    if (lane == 0) {
        atomicAdd(scal + 0, dsum);
        atomicAdd(scal + 1, dsq);
    }
}

__global__ __launch_bounds__(256) void pass2_kernel(
    const float* __restrict__ Abase, const float* __restrict__ Bbase,
    float* __restrict__ scal, int nslab)
{
    const int tid = threadIdx.x;
    const int g   = blockIdx.x * 256 + tid;
    const size_t slabElems = (size_t)DIMS * DIMS;
    float local = 0.f;
    for (int e = g; e < (int)slabElems; e += 65536) {
        float a = 0.f, b = 0.f;
        for (int s2 = 0; s2 < nslab; ++s2) {
            a += Abase[(size_t)s2 * slabElems + e];
            b += Bbase[(size_t)s2 * slabElems + e];
        }
        local += a * b;
    }
    for (int off = 32; off; off >>= 1) local += __shfl_xor(local, off);
    __shared__ float red[4];
    if ((tid & 63) == 0) red[tid >> 6] = local;
    __syncthreads();
    if (tid == 0) atomicAdd(scal + 2, red[0] + red[1] + red[2] + red[3]);
}

__global__ void finalize_kernel(const float* __restrict__ scal,
                                float* __restrict__ out)
{
    if (threadIdx.x == 0 && blockIdx.x == 0) {
        const double S   = (double)scal[2];
        const double dsq = (double)scal[1];
        const double ds  = (double)scal[0];
        const double off = S - dsq;
        const double loss =
            off / ((double)N_ROWS * (double)(N_ROWS - 1)) - 2.0 * ds / (double)N_ROWS;
        out[0] = (float)loss;
    }
}

extern "C" void kernel_launch(void* const* d_in, const int* in_sizes, int n_in,
                              void* d_out, int out_size, void* d_ws, size_t ws_size,
                              hipStream_t stream)
{
    const float* X = (const float*)d_in[0];
    const float* Y = (const float*)d_in[1];
    float* out = (float*)d_out;
    float* wsf = (float*)d_ws;

    const size_t trElems = (size_t)DIMS * N_ROWS;          // 4,194,304 bf16/matrix
    const size_t headB   = (64 + N_ROWS) * sizeof(float);  // scal + diagDot = 33 KB
    const size_t baseB   = headB + 2 * trElems * sizeof(u16);  // + Xh + Yh = 16.81 MB
    auto slabB = [](int ns) { return (size_t)ns * 2 * 10 * 16384 * sizeof(u16); };

    float* scal    = wsf;
    float* diagDot = wsf + 64;
    u16* Xh = (u16*)((char*)d_ws + headB);
    u16* Yh = Xh + trElems;

    int nsplit = 0;
    if      (ws_size >= baseB + slabB(32)) nsplit = 32;
    else if (ws_size >= baseB + slabB(16)) nsplit = 16;

    if (nsplit) {
        u16* slabs = (u16*)(Yh + trElems);
        hipMemsetAsync(d_ws, 0, headB, stream);
        convert_diag<<<1024, NT, 0, stream>>>(X, Y, Xh, Yh, diagDot);
        syrk_bf16<<<dim3(nsplit, 10, 2), NT, 0, stream>>>(
            Xh, Yh, slabs, nullptr, nullptr, N_ROWS / nsplit, 0);
        pass2_packed<<<80, 256, 0, stream>>>(slabs, diagDot, scal, nsplit);
        finalize_kernel<<<1, 64, 0, stream>>>(scal, out);
    } else if (ws_size >= baseB + 2 * (size_t)DIMS * DIMS * sizeof(float)) {
        // atomic fallback: fp32 A/B slabs
        float* Aslab = (float*)(Yh + trElems);
        float* Bslab = Aslab + DIMS * DIMS;
        hipMemsetAsync(d_ws, 0, headB, stream);
        hipMemsetAsync(Aslab, 0, 2 * (size_t)DIMS * DIMS * sizeof(float), stream);
        convert_diag<<<1024, NT, 0, stream>>>(X, Y, Xh, Yh, diagDot);
        syrk_bf16<<<dim3(32, 10, 2), NT, 0, stream>>>(
            Xh, Yh, nullptr, Aslab, Bslab, N_ROWS / 32, 1);
        pass2_sym<<<256, 256, 0, stream>>>(Aslab, Bslab, diagDot, scal);
        finalize_kernel<<<1, 64, 0, stream>>>(scal, out);
    } else {
        // fp32 vector fallback (round-1 path)
        const size_t slabElems = (size_t)DIMS * DIMS;
        const size_t hdr = 64;
        const bool slabs2 = ws_size >= (hdr + 16 * slabElems) * sizeof(float);
        const int  nslab = slabs2 ? KSPLIT : 1;
        float* Abase = wsf + hdr;
        float* Bbase = Abase + (size_t)nslab * slabElems;

        hipMemsetAsync(d_ws, 0, hdr * sizeof(float), stream);
        if (!slabs2) hipMemsetAsync(Abase, 0, 2 * slabElems * sizeof(float), stream);

        dim3 sg(64, KSPLIT);
        syrk_kernel<<<sg, NT, 0, stream>>>(X, Y, Abase, Bbase, slabs2 ? 1 : 0);
        diag_kernel<<<256, 256, 0, stream>>>(X, Y, wsf);
        pass2_kernel<<<256, 256, 0, stream>>>(Abase, Bbase, wsf, nslab);
        finalize_kernel<<<1, 64, 0, stream>>>(wsf, out);
    }
}

// Round 5
// 99.826 us; speedup vs baseline: 2.3711x; 1.0845x over previous
//
#include <hip/hip_runtime.h>
#include <cstdint>

#define N_ROWS 8192
#define DIMS   512
#define NT     256

typedef unsigned short u16;
typedef __attribute__((ext_vector_type(8))) short s8v;            // 8 bf16 MFMA A/B frag
typedef __attribute__((ext_vector_type(4))) float f4v;            // MFMA C/D frag
typedef __attribute__((ext_vector_type(8))) unsigned short u16x8;

__device__ __forceinline__ u16 f2bf(float f) {
    unsigned u = __float_as_uint(f);
    unsigned r = (u + 0x7fff + ((u >> 16) & 1)) >> 16;
    return (u16)r;
}
__device__ __forceinline__ float bf2f(u16 h) { return __uint_as_float(((unsigned)h) << 16); }

__device__ __forceinline__ void gl16(const void* g, void* l) {
    auto gp = (const __attribute__((address_space(1))) unsigned int*)(uintptr_t)g;
    auto lp = (__attribute__((address_space(3))) unsigned int*)(uintptr_t)l;
    __builtin_amdgcn_global_load_lds(gp, lp, 16, 0, 0);
}

// ============ convert + transpose (hi only) + diag partials (plain stores) ============
// grid: 1024 blocks (nt 0..127, dt 0..7). Writes Xh/Yh [512][8192] bf16 and
// diagPart[dt][8192] (each element written exactly once -> no zeroing needed).
__global__ __launch_bounds__(NT) void convert_diag(
    const float* __restrict__ X, const float* __restrict__ Y,
    u16* __restrict__ Xh, u16* __restrict__ Yh,
    float* __restrict__ diagPart)
{
    const int b  = blockIdx.x;
    const int nt = b & 127;
    const int dt = b >> 7;

    __shared__ float tx[64][65];
    __shared__ float ty[64][65];

    const int tid = threadIdx.x;
    const int c4 = tid & 15, rr = tid >> 4;
#pragma unroll
    for (int rp = 0; rp < 4; ++rp) {
        const int row = rp * 16 + rr;
        const size_t gbase = (size_t)(nt * 64 + row) * DIMS + dt * 64 + c4 * 4;
        float4 vx = *(const float4*)&X[gbase];
        float4 vy = *(const float4*)&Y[gbase];
        tx[row][c4 * 4 + 0] = vx.x; tx[row][c4 * 4 + 1] = vx.y;
        tx[row][c4 * 4 + 2] = vx.z; tx[row][c4 * 4 + 3] = vx.w;
        ty[row][c4 * 4 + 0] = vy.x; ty[row][c4 * 4 + 1] = vy.y;
        ty[row][c4 * 4 + 2] = vy.z; ty[row][c4 * 4 + 3] = vy.w;
        float d = vx.x * vy.x + vx.y * vy.y + vx.z * vy.z + vx.w * vy.w;
        d += __shfl_xor(d, 1); d += __shfl_xor(d, 2);
        d += __shfl_xor(d, 4); d += __shfl_xor(d, 8);
        if (c4 == 0) diagPart[dt * N_ROWS + nt * 64 + row] = d;
    }
    __syncthreads();

    const int d = tid >> 2, ns = (tid & 3) * 16;
    const size_t ob = (size_t)(dt * 64 + d) * N_ROWS + nt * 64 + ns;
#pragma unroll
    for (int mat = 0; mat < 2; ++mat) {
        float (*tp)[65] = mat ? ty : tx;
        u16* Oh = mat ? Yh : Xh;
        u16x8 h0, h1;
#pragma unroll
        for (int i = 0; i < 8; ++i) {
            h0[i] = f2bf(tp[ns + i][d]);
            h1[i] = f2bf(tp[ns + 8 + i][d]);
        }
        *(u16x8*)&Oh[ob]     = h0;
        *(u16x8*)&Oh[ob + 8] = h1;
    }
}

// ============ symmetric bf16 syrk, BK=32 double-buffer, 32 KB LDS ============
// grid (nsplit, 10, 2): x = k-split, y = upper tile pair, z = matrix.
// 4 blocks/CU co-resident (launch_bounds(256,4)) -> whole grid resident, no
// block-wave quantization. Per wave 64x64 = 4x4 16x16x32 tiles, 16 MFMA/iter.
// LDS [stripe][128 rows][32 k], chunk XOR swizzle c_phys = c ^ ((row>>1)&3)
// -> frag ds_read_b128 hit each bank granule exactly 2x (free).
__global__ __launch_bounds__(NT, 4) void syrk_bf16(
    const u16* __restrict__ Xh, const u16* __restrict__ Yh,
    u16* __restrict__ slabs, float* __restrict__ Aslab, float* __restrict__ Bslab,
    int kchunk, int mode)
{
    __shared__ u16 smem[2 * 2 * 4096];   // [stage][stripe][128*32] = 32 KB

    const int tid = threadIdx.x;
    const int s = blockIdx.x, p = blockIdx.y, mat = blockIdx.z;
    const int ti_t[10] = {0,0,0,0,1,1,1,2,2,3};
    const int tj_t[10] = {0,1,2,3,1,2,3,2,3,3};
    const int m0 = ti_t[p] * 128, n0 = tj_t[p] * 128;
    const u16* Th = mat ? Yh : Xh;

    const int w = tid >> 6, L = tid & 63;
    const int wm = (w >> 1) * 64, wn = (w & 1) * 64;
    const int lrow = L & 15, q = L >> 4;

    f4v acc[4][4];
#pragma unroll
    for (int i = 0; i < 4; ++i)
#pragma unroll
        for (int j = 0; j < 4; ++j)
            acc[i][j] = (f4v){0.f, 0.f, 0.f, 0.f};

    const int kk0 = s * kchunk;
    const int nIter = kchunk / 32;

    auto loadStage = [&](int buf, int kb) {
        u16* dA = smem + buf * 8192;
        u16* dB = dA + 4096;
#pragma unroll
        for (int j = 0; j < 2; ++j) {
            const int slot = j * 256 + tid;
            const int row  = slot >> 2;
            const int c    = (slot & 3) ^ ((row >> 1) & 3);
            gl16(Th + (size_t)(m0 + row) * N_ROWS + kb + c * 8, dA + slot * 8);
            gl16(Th + (size_t)(n0 + row) * N_ROWS + kb + c * 8, dB + slot * 8);
        }
    };

    loadStage(0, kk0);

    for (int it = 0; it < nIter; ++it) {
        __syncthreads();                 // drains stage-it gl16s, syncs block
        if (it + 1 < nIter) loadStage((it + 1) & 1, kk0 + (it + 1) * 32);

        const u16* SA = smem + (it & 1) * 8192;
        const u16* SB = SA + 4096;
        s8v a[4], b[4];
#pragma unroll
        for (int t = 0; t < 4; ++t) {
            const int rowA = wm + t * 16 + lrow;
            const int rowB = wn + t * 16 + lrow;
            const int pA = q ^ ((rowA >> 1) & 3);
            const int pB = q ^ ((rowB >> 1) & 3);
            a[t] = *(const s8v*)&SA[rowA * 32 + pA * 8];
            b[t] = *(const s8v*)&SB[rowB * 32 + pB * 8];
        }
#pragma unroll
        for (int ti2 = 0; ti2 < 4; ++ti2)
#pragma unroll
            for (int tj2 = 0; tj2 < 4; ++tj2)
                acc[ti2][tj2] = __builtin_amdgcn_mfma_f32_16x16x32_bf16(
                    a[ti2], b[tj2], acc[ti2][tj2], 0, 0, 0);
    }

    if (mode == 0) {
        u16* dst = slabs + ((size_t)(s * 2 + mat) * 10 + p) * 16384;
#pragma unroll
        for (int ti2 = 0; ti2 < 4; ++ti2)
#pragma unroll
            for (int tj2 = 0; tj2 < 4; ++tj2)
#pragma unroll
                for (int r = 0; r < 4; ++r) {
                    const int rl = wm + ti2 * 16 + q * 4 + r;
                    const int cl = wn + tj2 * 16 + lrow;
                    dst[rl * 128 + cl] = f2bf(acc[ti2][tj2][r]);
                }
    } else {
        float* G = mat ? Bslab : Aslab;
#pragma unroll
        for (int ti2 = 0; ti2 < 4; ++ti2)
#pragma unroll
            for (int tj2 = 0; tj2 < 4; ++tj2)
#pragma unroll
                for (int r = 0; r < 4; ++r) {
                    const int row = m0 + wm + ti2 * 16 + q * 4 + r;
                    const int col = n0 + wn + tj2 * 16 + lrow;
                    atomicAdd(&G[row * DIMS + col], acc[ti2][tj2][r]);
                }
    }
}

// ============ pass2 (bf16 slabs): batched loads, per-block partials ============
// grid 80 x 256 = 20480 threads; each owns 8 consecutive elems of one tile.
__global__ __launch_bounds__(256) void pass2_packed(
    const u16* __restrict__ slabs, const float* __restrict__ diagPart,
    float4* __restrict__ partials, int nsplit)
{
    const int tid = threadIdx.x;
    const int g   = blockIdx.x * 256 + tid;        // 0..20479
    const int p   = g >> 11;                       // tile pair 0..9
    const int e8  = (g & 2047) * 8;
    const float wp = ((p == 0) | (p == 4) | (p == 7) | (p == 9)) ? 1.f : 2.f;

    float a[8] = {}, b[8] = {};
    for (int sb = 0; sb < nsplit; sb += 8) {
        u16x8 va[8], vb[8];
#pragma unroll
        for (int i = 0; i < 8; ++i) {
            va[i] = *(const u16x8*)&slabs[((size_t)((sb + i) * 2 + 0) * 10 + p) * 16384 + e8];
            vb[i] = *(const u16x8*)&slabs[((size_t)((sb + i) * 2 + 1) * 10 + p) * 16384 + e8];
        }
#pragma unroll
        for (int i = 0; i < 8; ++i)
#pragma unroll
            for (int j = 0; j < 8; ++j) {
                a[j] += bf2f(va[i][j]);
                b[j] += bf2f(vb[i][j]);
            }
    }
    float sS = 0.f;
#pragma unroll
    for (int j = 0; j < 8; ++j) sS += a[j] * b[j];
    sS *= wp;

    float sD = 0.f, sD2 = 0.f;
    if (g < N_ROWS) {
        float d = 0.f;
#pragma unroll
        for (int dt = 0; dt < 8; ++dt) d += diagPart[dt * N_ROWS + g];
        sD = d; sD2 = d * d;
    }

    for (int off = 32; off; off >>= 1) {
        sS  += __shfl_xor(sS,  off);
        sD  += __shfl_xor(sD,  off);
        sD2 += __shfl_xor(sD2, off);
    }
    __shared__ float red[3][4];
    if ((tid & 63) == 0) {
        red[0][tid >> 6] = sS; red[1][tid >> 6] = sD; red[2][tid >> 6] = sD2;
    }
    __syncthreads();
    if (tid == 0)
        partials[blockIdx.x] = make_float4(
            red[0][0] + red[0][1] + red[0][2] + red[0][3],
            red[1][0] + red[1][1] + red[1][2] + red[1][3],
            red[2][0] + red[2][1] + red[2][2] + red[2][3], 0.f);
}

// ============ pass2 for atomic-slab tier (fp32 slabs + diagPart) ============
__global__ __launch_bounds__(256) void pass2_sym(
    const float* __restrict__ Aslab, const float* __restrict__ Bslab,
    const float* __restrict__ diagPart, float4* __restrict__ partials)
{
    const int tid = threadIdx.x;
    const int g   = blockIdx.x * 256 + tid;        // 0..20479
    float sS = 0.f, sD = 0.f, sD2 = 0.f;
    for (int e = g; e < DIMS * DIMS; e += 20480) {
        const int r = e >> 9, c = e & 511;
        const float w = ((r >> 7) == (c >> 7)) ? 1.f : 2.f;
        sS += w * Aslab[e] * Bslab[e];
    }
    if (g < N_ROWS) {
        float d = 0.f;
#pragma unroll
        for (int dt = 0; dt < 8; ++dt) d += diagPart[dt * N_ROWS + g];
        sD = d; sD2 = d * d;
    }
    for (int off = 32; off; off >>= 1) {
        sS  += __shfl_xor(sS,  off);
        sD  += __shfl_xor(sD,  off);
        sD2 += __shfl_xor(sD2, off);
    }
    __shared__ float red[3][4];
    if ((tid & 63) == 0) {
        red[0][tid >> 6] = sS; red[1][tid >> 6] = sD; red[2][tid >> 6] = sD2;
    }
    __syncthreads();
    if (tid == 0)
        partials[blockIdx.x] = make_float4(
            red[0][0] + red[0][1] + red[0][2] + red[0][3],
            red[1][0] + red[1][1] + red[1][2] + red[1][3],
            red[2][0] + red[2][1] + red[2][2] + red[2][3], 0.f);
}

// ============ finalize from per-block partials (one wave) ============
__global__ void finalize_partials(const float4* __restrict__ partials, int nb,
                                  float* __restrict__ out)
{
    const int tid = threadIdx.x;   // 64 threads
    float sS = 0.f, sD = 0.f, sD2 = 0.f;
    for (int i = tid; i < nb; i += 64) {
        float4 v = partials[i];
        sS += v.x; sD += v.y; sD2 += v.z;
    }
    for (int off = 32; off; off >>= 1) {
        sS  += __shfl_xor(sS,  off);
        sD  += __shfl_xor(sD,  off);
        sD2 += __shfl_xor(sD2, off);
    }
    if (tid == 0) {
        const double offd = (double)sS - (double)sD2;
        const double loss =
            offd / ((double)N_ROWS * (double)(N_ROWS - 1)) - 2.0 * (double)sD / (double)N_ROWS;
        out[0] = (float)loss;
    }
}

// ============ fp32 vector fallback (round-1, proven) ============
#define TILE   64
#define KSPLIT 8
#define KCHUNK (N_ROWS / KSPLIT)
#define KB     16
__global__ __launch_bounds__(NT) void syrk_kernel(
    const float* __restrict__ X, const float* __restrict__ Y,
    float* __restrict__ Abase, float* __restrict__ Bbase, int useSlabs)
{
    const int tid = threadIdx.x;
    const int ta  = blockIdx.x >> 3;
    const int tb  = blockIdx.x & 7;
    const int s   = blockIdx.y;
    const int ca  = tid & 15;
    const int cb  = tid >> 4;

    __shared__ float4 sXA[KB * 16];
    __shared__ float4 sXB[KB * 16];
    __shared__ float4 sYA[KB * 16];
    __shared__ float4 sYB[KB * 16];

    const float4* Xv = (const float4*)X;
    const float4* Yv = (const float4*)Y;

    float aA[4][4] = {};
    float aB[4][4] = {};

    const int r0     = s * KCHUNK;
    const int rowOfT = tid >> 4;
    const int colOfT = tid & 15;

    for (int it = 0; it < KCHUNK / KB; ++it) {
        const int row  = r0 + it * KB + rowOfT;
        const int base = row * (DIMS / 4);
        __syncthreads();
        sXA[tid] = Xv[base + ta * 16 + colOfT];
        sXB[tid] = Xv[base + tb * 16 + colOfT];
        sYA[tid] = Yv[base + ta * 16 + colOfT];
        sYB[tid] = Yv[base + tb * 16 + colOfT];
        __syncthreads();
#pragma unroll
        for (int k = 0; k < KB; ++k) {
            float4 xa4 = sXA[k * 16 + ca];
            float4 xb4 = sXB[k * 16 + cb];
            float4 ya4 = sYA[k * 16 + ca];
            float4 yb4 = sYB[k * 16 + cb];
            float xa[4] = {xa4.x, xa4.y, xa4.z, xa4.w};
            float xb[4] = {xb4.x, xb4.y, xb4.z, xb4.w};
            float ya[4] = {ya4.x, ya4.y, ya4.z, ya4.w};
            float yb[4] = {yb4.x, yb4.y, yb4.z, yb4.w};
#pragma unroll
            for (int i = 0; i < 4; ++i)
#pragma unroll
                for (int j = 0; j < 4; ++j) {
                    aA[i][j] = fmaf(xa[i], xb[j], aA[i][j]);
                    aB[i][j] = fmaf(ya[i], yb[j], aB[i][j]);
                }
        }
    }

    const size_t slabElems = (size_t)DIMS * DIMS;
    float* Adst = Abase + (useSlabs ? (size_t)s * slabElems : 0);
    float* Bdst = Bbase + (useSlabs ? (size_t)s * slabElems : 0);

#pragma unroll
    for (int i = 0; i < 4; ++i) {
        const int    ag    = ta * TILE + ca * 4 + i;
        const int    cbase = tb * TILE + cb * 4;
        const size_t idx   = (size_t)ag * DIMS + cbase;
        if (useSlabs) {
            *(float4*)(Adst + idx) = make_float4(aA[i][0], aA[i][1], aA[i][2], aA[i][3]);
            *(float4*)(Bdst + idx) = make_float4(aB[i][0], aB[i][1], aB[i][2], aB[i][3]);
        } else {
#pragma unroll
            for (int j = 0; j < 4; ++j) {
                atomicAdd(Adst + idx + j, aA[i][j]);
                atomicAdd(Bdst + idx + j, aB[i][j]);
            }
        }
    }
}

__global__ __launch_bounds__(256) void diag_kernel(
    const float* __restrict__ X, const float* __restrict__ Y,
    float* __restrict__ scal)
{
    const int tid  = threadIdx.x;
    const int lane = tid & 63;
    const int wave = blockIdx.x * 4 + (tid >> 6);
    const float4* Xv = (const float4*)X;
    const float4* Yv = (const float4*)Y;

    float dsum = 0.f, dsq = 0.f;
    for (int r = 0; r < 8; ++r) {
        const int row  = wave * 8 + r;
        const int base = row * (DIMS / 4) + lane * 2;
        float4 x0 = Xv[base], x1 = Xv[base + 1];
        float4 y0 = Yv[base], y1 = Yv[base + 1];
        float v = x0.x * y0.x + x0.y * y0.y + x0.z * y0.z + x0.w * y0.w
                + x1.x * y1.x + x1.y * y1.y + x1.z * y1.z + x1.w * y1.w;
        for (int off = 32; off; off >>= 1) v += __shfl_xor(v, off);
        if (lane == 0) { dsum += v; dsq += v * v; }
    }
    if (lane == 0) {
        atomicAdd(scal + 0, dsum);
        atomicAdd(scal + 1, dsq);
    }
}

__global__ __launch_bounds__(256) void pass2_kernel(
    const float* __restrict__ Abase, const float* __restrict__ Bbase,
    float* __restrict__ scal, int nslab)
{
    const int tid = threadIdx.x;
    const int g   = blockIdx.x * 256 + tid;
    const size_t slabElems = (size_t)DIMS * DIMS;
    float local = 0.f;
    for (int e = g; e < (int)slabElems; e += 65536) {
        float a = 0.f, b = 0.f;
        for (int s2 = 0; s2 < nslab; ++s2) {
            a += Abase[(size_t)s2 * slabElems + e];
            b += Bbase[(size_t)s2 * slabElems + e];
        }
        local += a * b;
    }
    for (int off = 32; off; off >>= 1) local += __shfl_xor(local, off);
    __shared__ float red[4];
    if ((tid & 63) == 0) red[tid >> 6] = local;
    __syncthreads();
    if (tid == 0) atomicAdd(scal + 2, red[0] + red[1] + red[2] + red[3]);
}

__global__ void finalize_kernel(const float* __restrict__ scal,
                                float* __restrict__ out)
{
    if (threadIdx.x == 0 && blockIdx.x == 0) {
        const double S   = (double)scal[2];
        const double dsq = (double)scal[1];
        const double ds  = (double)scal[0];
        const double off = S - dsq;
        const double loss =
            off / ((double)N_ROWS * (double)(N_ROWS - 1)) - 2.0 * ds / (double)N_ROWS;
        out[0] = (float)loss;
    }
}

extern "C" void kernel_launch(void* const* d_in, const int* in_sizes, int n_in,
                              void* d_out, int out_size, void* d_ws, size_t ws_size,
                              hipStream_t stream)
{
    const float* X = (const float*)d_in[0];
    const float* Y = (const float*)d_in[1];
    float* out = (float*)d_out;
    float* wsf = (float*)d_ws;

    const size_t trElems = (size_t)DIMS * N_ROWS;             // 4,194,304 bf16/matrix
    // Layout: [partials 80xfloat4 | diagPart 8x8192 f32 | Xh | Yh | slabs...]
    const size_t partF  = 320;
    const size_t diagF  = 8 * N_ROWS;
    const size_t coreB  = (partF + diagF) * sizeof(float) + 2 * trElems * sizeof(u16);
    auto slabB = [](int ns) { return (size_t)ns * 2 * 10 * 16384 * sizeof(u16); };

    float4* partials = (float4*)wsf;
    float*  diagPart = wsf + partF;
    u16* Xh = (u16*)(diagPart + diagF);
    u16* Yh = Xh + trElems;

    int nsplit = 0;
    if      (ws_size >= coreB + slabB(32)) nsplit = 32;
    else if (ws_size >= coreB + slabB(16)) nsplit = 16;

    if (nsplit) {
        // primary: no memsets, no global atomics anywhere
        u16* slabs = (u16*)(Yh + trElems);
        convert_diag<<<1024, NT, 0, stream>>>(X, Y, Xh, Yh, diagPart);
        syrk_bf16<<<dim3(nsplit, 10, 2), NT, 0, stream>>>(
            Xh, Yh, slabs, nullptr, nullptr, N_ROWS / nsplit, 0);
        pass2_packed<<<80, 256, 0, stream>>>(slabs, diagPart, partials, nsplit);
        finalize_partials<<<1, 64, 0, stream>>>(partials, 80, out);
    } else if (ws_size >= coreB + 2 * (size_t)DIMS * DIMS * sizeof(float)) {
        // atomic tier: fp32 A/B slabs
        float* Aslab = (float*)(Yh + trElems);
        float* Bslab = Aslab + DIMS * DIMS;
        hipMemsetAsync(Aslab, 0, 2 * (size_t)DIMS * DIMS * sizeof(float), stream);
        convert_diag<<<1024, NT, 0, stream>>>(X, Y, Xh, Yh, diagPart);
        syrk_bf16<<<dim3(32, 10, 2), NT, 0, stream>>>(
            Xh, Yh, nullptr, Aslab, Bslab, N_ROWS / 32, 1);
        pass2_sym<<<80, 256, 0, stream>>>(Aslab, Bslab, diagPart, partials);
        finalize_partials<<<1, 64, 0, stream>>>(partials, 80, out);
    } else {
        // fp32 vector fallback (round-1 path)
        const size_t slabElems = (size_t)DIMS * DIMS;
        const size_t hdr = 64;
        const bool slabs2 = ws_size >= (hdr + 16 * slabElems) * sizeof(float);
        const int  nslab = slabs2 ? KSPLIT : 1;
        float* Abase = wsf + hdr;
        float* Bbase = Abase + (size_t)nslab * slabElems;

        hipMemsetAsync(d_ws, 0, hdr * sizeof(float), stream);
        if (!slabs2) hipMemsetAsync(Abase, 0, 2 * slabElems * sizeof(float), stream);

        dim3 sg(64, KSPLIT);
        syrk_kernel<<<sg, NT, 0, stream>>>(X, Y, Abase, Bbase, slabs2 ? 1 : 0);
        diag_kernel<<<256, 256, 0, stream>>>(X, Y, wsf);
        pass2_kernel<<<256, 256, 0, stream>>>(Abase, Bbase, wsf, nslab);
        finalize_kernel<<<1, 64, 0, stream>>>(wsf, out);
    }
}